// Round 2
// baseline (66.425 us; speedup 1.0000x reference)
//
#include <hip/hip_runtime.h>
#include <hip/hip_bf16.h>
#include <stdint.h>

// Problem constants (from reference)
#define N_SAMP 16384
#define DCONT  64
#define DCAT   2000
#define EMB    64
#define K_CAT_PAD 2048          // 16 tiles of 128 (rows 2000..2047 zero-padded in B)
#define K_PAD     2112          // + 64 continuous K at the end
#define BM 32
#define BK 128
#define NT_CAT 16
#define NT 17                   // 16 cat tiles + 1 cont tile

typedef short bf16x8 __attribute__((ext_vector_type(8)));
typedef float f32x4  __attribute__((ext_vector_type(4)));

__device__ __forceinline__ uint16_t f2bf(float f) {
    union { float f; uint32_t u; } v; v.f = f;
    uint32_t r = v.u + 0x7FFFu + ((v.u >> 16) & 1u);   // RNE
    return (uint16_t)(r >> 16);
}
__device__ __forceinline__ uint32_t pack2mask(int a, int b) {
    // two int mask values -> two packed bf16 (1.0f = 0x3F80, 0.0f = 0)
    return (a ? 0x3F80u : 0u) | (b ? 0x3F800000u : 0u);
}
__device__ __forceinline__ uint32_t pack2f(float a, float b) {
    return (uint32_t)f2bf(a) | ((uint32_t)f2bf(b) << 16);
}

// Build B_T[c][k] (bf16), c in [0,64), k in [0,2112):
//   k <  2000          : W_cat[k][c]
//   2000 <= k < 2048   : 0   (pad so cat phase is 16 aligned BK=128 tiles)
//   2048 <= k < 2112   : W_cont[k-2048][c]
__global__ void build_b_kernel(const float* __restrict__ Wcont,
                               const float* __restrict__ Wcat,
                               uint16_t* __restrict__ Bws) {
    int k = blockIdx.x * 64 + threadIdx.x;   // 0..2111, coalesced writes along k
    int c = blockIdx.y;                      // 0..63
    float v = 0.f;
    if (k < DCAT)            v = Wcat[(long)k * EMB + c];
    else if (k >= K_CAT_PAD) v = Wcont[(long)(k - K_CAT_PAD) * EMB + c];
    Bws[(long)c * K_PAD + k] = f2bf(v);
}

__global__ __launch_bounds__(256, 2)
void fm_kernel(const float* __restrict__ xc,
               const int*   __restrict__ xcat,
               const uint16_t* __restrict__ Bws,
               float* __restrict__ out) {
    // LDS: double-buffered A[32][128] bf16 (256B rows) and B_T[64][128] bf16 (256B rows)
    __shared__ int4 AbufI[2][BM * 16];
    __shared__ int4 BbufI[2][EMB * 16];
    __shared__ float part[2][BM];

    const int tid = threadIdx.x;
    const int r0  = blockIdx.x * BM;

    // staging maps: A = 8 thr/row x 64B, B = 4 thr/col x 64B
    const int aRow = tid >> 3, aCh = tid & 7;
    const int bCol = tid >> 2, bCh = tid & 3;

    // compute maps: 4 waves = 2M x 2N; each wave 16 rows x 32 cols
    const int w = tid >> 6, lane = tid & 63;
    const int wm = w >> 1, wn = w & 1;
    const int g = lane >> 4, lr = lane & 15;

    int4 ra[4]; float4 raf[2]; int4 rb[4];
    f32x4 acc[2] = { {0.f,0.f,0.f,0.f}, {0.f,0.f,0.f,0.f} };

    const long aBase  = (long)(r0 + aRow) * DCAT;    // ints
    const long a2Base = (long)(r0 + aRow) * DCONT;   // floats
    const long bBaseB = (long)bCol * K_PAD * 2;      // bytes into Bws

    auto stageLoadCat = [&](int t) {
        #pragma unroll
        for (int j = 0; j < 4; ++j) {
            int cl = (aCh * 4 + j) * 4;        // int offset within tile, mult of 4
            int c  = t * BK + cl;
            if (c < DCAT) ra[j] = *(const int4*)(xcat + aBase + c);
            else          ra[j] = make_int4(0, 0, 0, 0);
        }
        #pragma unroll
        for (int j = 0; j < 4; ++j)
            rb[j] = *(const int4*)((const char*)Bws + bBaseB + t * 256 + bCh * 64 + j * 16);
    };
    auto stageLoadCont = [&]() {
        raf[0] = *(const float4*)(xc + a2Base + aCh * 8);
        raf[1] = *(const float4*)(xc + a2Base + aCh * 8 + 4);
        #pragma unroll
        for (int j = 0; j < 2; ++j)
            rb[j] = *(const int4*)((const char*)Bws + bBaseB + K_CAT_PAD * 2 + bCh * 32 + j * 16);
    };
    auto stageWriteCat = [&](int buf) {
        uint32_t p[8];
        #pragma unroll
        for (int j = 0; j < 4; ++j) {
            p[2 * j]     = pack2mask(ra[j].x, ra[j].y);
            p[2 * j + 1] = pack2mask(ra[j].z, ra[j].w);
        }
        const int sw = (aRow & 7) << 4;
        char* abase = (char*)AbufI[buf] + aRow * 256;
        *(int4*)(abase + ((aCh * 32)      ^ sw)) = make_int4(p[0], p[1], p[2], p[3]);
        *(int4*)(abase + ((aCh * 32 + 16) ^ sw)) = make_int4(p[4], p[5], p[6], p[7]);
        const int swb = (bCol & 7) << 4;
        char* bbase = (char*)BbufI[buf] + bCol * 256;
        #pragma unroll
        for (int j = 0; j < 4; ++j)
            *(int4*)(bbase + ((bCh * 64 + j * 16) ^ swb)) = rb[j];
    };
    auto stageWriteCont = [&](int buf) {
        uint32_t p[4];
        p[0] = pack2f(raf[0].x, raf[0].y); p[1] = pack2f(raf[0].z, raf[0].w);
        p[2] = pack2f(raf[1].x, raf[1].y); p[3] = pack2f(raf[1].z, raf[1].w);
        const int sw = (aRow & 7) << 4;
        char* abase = (char*)AbufI[buf] + aRow * 256;
        *(int4*)(abase + ((aCh * 16) ^ sw)) = make_int4(p[0], p[1], p[2], p[3]);
        const int swb = (bCol & 7) << 4;
        char* bbase = (char*)BbufI[buf] + bCol * 256;
        #pragma unroll
        for (int j = 0; j < 2; ++j)
            *(int4*)(bbase + ((bCh * 32 + j * 16) ^ swb)) = rb[j];
    };
    auto compute = [&](int buf, int nk) {
        const int arow = wm * 16 + lr;
        const int asw = (arow & 7) << 4;
        const char* abase = (const char*)AbufI[buf] + arow * 256;
        const char* bbase0 = (const char*)BbufI[buf];
        for (int kk = 0; kk < nk; ++kk) {
            bf16x8 af = *(const bf16x8*)(abase + ((kk * 64 + g * 16) ^ asw));
            #pragma unroll
            for (int nf = 0; nf < 2; ++nf) {
                const int c = wn * 32 + nf * 16 + lr;
                bf16x8 bfr = *(const bf16x8*)(bbase0 + c * 256 + ((kk * 64 + g * 16) ^ ((c & 7) << 4)));
                acc[nf] = __builtin_amdgcn_mfma_f32_16x16x32_bf16(af, bfr, acc[nf], 0, 0, 0);
            }
        }
    };

    // prologue: stage tile 0
    stageLoadCat(0);
    stageWriteCat(0);
    __syncthreads();

    for (int t = 0; t < NT; ++t) {
        const int cur = t & 1;
        // T14: issue next tile's global loads before compute
        if (t < NT - 1) {
            if (t + 1 < NT_CAT) stageLoadCat(t + 1);
            else                stageLoadCont();
        }
        compute(cur, (t == NT - 1) ? 2 : 4);
        __syncthreads();
        if (t < NT - 1) {
            if (t + 1 < NT_CAT) stageWriteCat(cur ^ 1);
            else                stageWriteCont(cur ^ 1);
            __syncthreads();
        }
    }

    // epilogue: out[r] = 0.5 * sum_c s[r][c]^2
    // lane holds cols wn*32 + nf*16 + lr, rows wm*16 + g*4 + reg
    #pragma unroll
    for (int r = 0; r < 4; ++r) {
        float p = acc[0][r] * acc[0][r] + acc[1][r] * acc[1][r];
        p += __shfl_xor(p, 1);
        p += __shfl_xor(p, 2);
        p += __shfl_xor(p, 4);
        p += __shfl_xor(p, 8);
        if (lr == 0) part[wn][wm * 16 + g * 4 + r] = p;
    }
    __syncthreads();
    if (tid < BM) out[r0 + tid] = 0.5f * (part[0][tid] + part[1][tid]);
}

extern "C" void kernel_launch(void* const* d_in, const int* in_sizes, int n_in,
                              void* d_out, int out_size, void* d_ws, size_t ws_size,
                              hipStream_t stream) {
    const float* xc    = (const float*)d_in[0];   // data_continuous [N,64] f32
    const int*   xcat  = (const int*)d_in[1];     // data_category   [N,2000] i32
    const float* Wcont = (const float*)d_in[2];   // [64,64] f32
    const float* Wcat  = (const float*)d_in[3];   // [2000,64] f32
    uint16_t* Bws = (uint16_t*)d_ws;              // B_T[64][2112] bf16 = 264 KiB
    float* outp = (float*)d_out;

    build_b_kernel<<<dim3(K_PAD / 64, EMB), 64, 0, stream>>>(Wcont, Wcat, Bws);
    fm_kernel<<<N_SAMP / BM, 256, 0, stream>>>(xc, xcat, Bws, outp);
}

// Round 3
// 51.329 us; speedup vs baseline: 1.2941x; 1.2941x over previous
//
#include <hip/hip_runtime.h>
#include <hip/hip_bf16.h>
#include <stdint.h>

// Problem constants (from reference)
#define N_SAMP 16384
#define DCONT  64
#define DCAT   2000
#define EMB    64
#define K_CAT_PAD 2048          // 64 K-steps of 32 (k 2000..2047 zero-padded in B)
#define K_PAD     2112          // + 64 continuous K at the end

typedef short bf16x8 __attribute__((ext_vector_type(8)));
typedef float f32x4  __attribute__((ext_vector_type(4)));

__device__ __forceinline__ uint16_t f2bf(float f) {
    union { float f; uint32_t u; } v; v.f = f;
    uint32_t r = v.u + 0x7FFFu + ((v.u >> 16) & 1u);   // RNE
    return (uint16_t)(r >> 16);
}
__device__ __forceinline__ uint32_t pack2f(float a, float b) {
    return (uint32_t)f2bf(a) | ((uint32_t)f2bf(b) << 16);
}

// Build B_T[c][k] (bf16), c in [0,64), k in [0,2112):
//   k <  2000          : W_cat[k][c]
//   2000 <= k < 2048   : 0   (pad so the cat phase is 64 aligned K=32 steps)
//   2048 <= k < 2112   : W_cont[k-2048][c]
__global__ void build_b_kernel(const float* __restrict__ Wcont,
                               const float* __restrict__ Wcat,
                               uint16_t* __restrict__ Bws) {
    int k = blockIdx.x * 64 + threadIdx.x;   // coalesced along k
    int c = blockIdx.y;
    float v = 0.f;
    if (k < DCAT)            v = Wcat[(long)k * EMB + c];
    else if (k >= K_CAT_PAD) v = Wcont[(long)(k - K_CAT_PAD) * EMB + c];
    Bws[(long)c * K_PAD + k] = f2bf(v);
}

struct AFrag { int4 a0, a1; };
struct BFrag { bf16x8 b0, b1, b2, b3; };

__global__ __launch_bounds__(256, 4)
void fm_kernel(const float* __restrict__ xc,
               const int*   __restrict__ xcat,
               const uint16_t* __restrict__ Bws,
               float* __restrict__ out) {
    // 4 waves per block; each wave computes a PARTIAL s for the same 16 rows
    // over a quarter of K (no barriers in the main loop). Epilogue combines.
    __shared__ float part[4][16][EMB];

    const int tid  = threadIdx.x;
    const int w    = tid >> 6;
    const int lane = tid & 63;
    const int g    = lane >> 4;        // k-chunk within fragment (8 elems)
    const int lr   = lane & 15;        // row (A) / col (B) within tile
    const int r0   = blockIdx.x * 16;

    f32x4 acc[4] = { {0,0,0,0}, {0,0,0,0}, {0,0,0,0}, {0,0,0,0} };

    const long aBase = (long)(r0 + lr) * DCAT;   // xcat row base (ints)
    const int  kw    = w * 512;                  // this wave's cat k-range start

    auto loadA = [&](int kbase) -> AFrag {
        AFrag f;
        const int kg = kbase + g * 8;
        if (kg + 8 <= DCAT) {
            f.a0 = *(const int4*)(xcat + aBase + kg);
            f.a1 = *(const int4*)(xcat + aBase + kg + 4);
        } else {
            f.a0 = make_int4(0, 0, 0, 0);
            f.a1 = make_int4(0, 0, 0, 0);
        }
        return f;
    };
    auto loadB = [&](int kbase) -> BFrag {
        BFrag f;
        const int kg = kbase + g * 8;
        f.b0 = *(const bf16x8*)(Bws + (long)(0 * 16 + lr) * K_PAD + kg);
        f.b1 = *(const bf16x8*)(Bws + (long)(1 * 16 + lr) * K_PAD + kg);
        f.b2 = *(const bf16x8*)(Bws + (long)(2 * 16 + lr) * K_PAD + kg);
        f.b3 = *(const bf16x8*)(Bws + (long)(3 * 16 + lr) * K_PAD + kg);
        return f;
    };
    // mask int {0,1} -> bf16 {0.0, 1.0}: (a + (b<<16)) * 0x3F80, 24-bit safe
    auto catFrag = [&](AFrag A) -> bf16x8 {
        union { uint32_t u[4]; bf16x8 v; } cv;
        cv.u[0] = (uint32_t)((A.a0.x + (A.a0.y << 16)) * 0x3F80u);
        cv.u[1] = (uint32_t)((A.a0.z + (A.a0.w << 16)) * 0x3F80u);
        cv.u[2] = (uint32_t)((A.a1.x + (A.a1.y << 16)) * 0x3F80u);
        cv.u[3] = (uint32_t)((A.a1.z + (A.a1.w << 16)) * 0x3F80u);
        return cv.v;
    };
    auto mmac = [&](bf16x8 af, const BFrag& B) {
        acc[0] = __builtin_amdgcn_mfma_f32_16x16x32_bf16(af, B.b0, acc[0], 0, 0, 0);
        acc[1] = __builtin_amdgcn_mfma_f32_16x16x32_bf16(af, B.b1, acc[1], 0, 0, 0);
        acc[2] = __builtin_amdgcn_mfma_f32_16x16x32_bf16(af, B.b2, acc[2], 0, 0, 0);
        acc[3] = __builtin_amdgcn_mfma_f32_16x16x32_bf16(af, B.b3, acc[3], 0, 0, 0);
    };

    // --- cat main loop: 16 K-steps of 32, register double-buffered, no barriers
    AFrag ac = loadA(kw);
    BFrag bc = loadB(kw);
    AFrag an; BFrag bn;
    #pragma unroll 2
    for (int s = 0; s < 16; s += 2) {
        an = loadA(kw + (s + 1) * 32);
        bn = loadB(kw + (s + 1) * 32);
        mmac(catFrag(ac), bc);
        if (s + 2 < 16) {
            ac = loadA(kw + (s + 2) * 32);
            bc = loadB(kw + (s + 2) * 32);
        }
        mmac(catFrag(an), bn);
    }

    // --- continuous part: waves 2 and 3 take one 32-wide K-step each
    if (w >= 2) {
        const int cs = w - 2;                       // 0 or 1
        const long cBase = (long)(r0 + lr) * DCONT + cs * 32 + g * 8;
        float4 x0 = *(const float4*)(xc + cBase);
        float4 x1 = *(const float4*)(xc + cBase + 4);
        BFrag bcc = loadB(K_CAT_PAD + cs * 32);
        union { uint32_t u[4]; bf16x8 v; } cv;
        cv.u[0] = pack2f(x0.x, x0.y);
        cv.u[1] = pack2f(x0.z, x0.w);
        cv.u[2] = pack2f(x1.x, x1.y);
        cv.u[3] = pack2f(x1.z, x1.w);
        mmac(cv.v, bcc);
    }

    // --- epilogue: combine 4 wave-partials, out[r] = 0.5 * ||s_row||^2
    // lane (g,lr) holds rows g*4+r, col n*16+lr
    #pragma unroll
    for (int n = 0; n < 4; ++n) {
        #pragma unroll
        for (int r = 0; r < 4; ++r)
            part[w][g * 4 + r][n * 16 + lr] = acc[n][r];
    }
    __syncthreads();

    const int row = tid >> 4;            // 0..15
    const int c0  = (tid & 15) * 4;      // 4 cols per thread
    float4 v0 = *(const float4*)&part[0][row][c0];
    float4 v1 = *(const float4*)&part[1][row][c0];
    float4 v2 = *(const float4*)&part[2][row][c0];
    float4 v3 = *(const float4*)&part[3][row][c0];
    float sx = v0.x + v1.x + v2.x + v3.x;
    float sy = v0.y + v1.y + v2.y + v3.y;
    float sz = v0.z + v1.z + v2.z + v3.z;
    float sw_ = v0.w + v1.w + v2.w + v3.w;
    float p = sx * sx + sy * sy + sz * sz + sw_ * sw_;
    p += __shfl_xor(p, 1);
    p += __shfl_xor(p, 2);
    p += __shfl_xor(p, 4);
    p += __shfl_xor(p, 8);
    if ((tid & 15) == 0) out[r0 + row] = 0.5f * p;
}

extern "C" void kernel_launch(void* const* d_in, const int* in_sizes, int n_in,
                              void* d_out, int out_size, void* d_ws, size_t ws_size,
                              hipStream_t stream) {
    const float* xc    = (const float*)d_in[0];   // data_continuous [N,64] f32
    const int*   xcat  = (const int*)d_in[1];     // data_category   [N,2000] i32
    const float* Wcont = (const float*)d_in[2];   // [64,64] f32
    const float* Wcat  = (const float*)d_in[3];   // [2000,64] f32
    uint16_t* Bws = (uint16_t*)d_ws;              // B_T[64][2112] bf16 = 264 KiB
    float* outp = (float*)d_out;

    build_b_kernel<<<dim3(K_PAD / 64, EMB), 64, 0, stream>>>(Wcont, Wcat, Bws);
    fm_kernel<<<N_SAMP / 16, 256, 0, stream>>>(xc, xcat, Bws, outp);
}